// Round 5
// baseline (313.166 us; speedup 1.0000x reference)
//
#include <hip/hip_runtime.h>
#include <math.h>

#define NROWS   16384
#define NBOOKS  128
#define NWORDS  64
#define LWORD   32
#define DIMS    4096
#define TAU_K   14.4269504088896340736f   /* 10 * log2(e)  */
#define T2K     28.8539008177792681472f   /* 20 * log2(e)  */
#define Z_ELEMS 67108864ull               /* 16384*4096    */

typedef __attribute__((ext_vector_type(8))) short s16x8;
typedef __attribute__((ext_vector_type(4))) float f32x4;
typedef __attribute__((ext_vector_type(4))) unsigned int u32x4;

/* ws layout (bytes) */
#define CBT_OFF  0u           /* f32 [128][64][32] np-normalized codewords  */
#define C2T_OFF  1048576u     /* f32 [128][64]                              */
#define CHA_OFF  1081344u     /* bf16 S-frags hi                            */
#define CLA_OFF  1605632u     /* bf16 S-frags lo                            */
#define A2_OFF   2129920u     /* bf16 Z-frags                               */
#define C2I_OFF  2654208u     /* f32x4 acc-init = -c2/2                     */
#define CTR_OFF  3178496u     /* u32 rescan counter                         */
#define LIST_OFF 3178624u     /* u32[131072] packed (row<<7)|b              */
#define LIST_CAP 131072u

__device__ __forceinline__ unsigned short f2bf(float f) {
    unsigned int u = __float_as_uint(f);
    unsigned int r = (u + 0x7FFFu + ((u >> 16) & 1u)) >> 16;   /* RNE */
    return (unsigned short)r;
}
__device__ __forceinline__ float bf2f(unsigned short s) {
    return __uint_as_float(((unsigned int)s) << 16);
}
__device__ __forceinline__ unsigned int cvtpk_bf16(float lo, float hi) {
    unsigned int r;
    asm("v_cvt_pk_bf16_f32 %0, %1, %2" : "=v"(r) : "v"(lo), "v"(hi));  /* RNE */
    return r;
}

/* numpy pairwise-sum replica for n=32 f32 (exact order, no contraction) */
__device__ __forceinline__ float np_sum32(const float* a) {
#pragma clang fp contract(off)
    float r0 = a[0], r1 = a[1], r2 = a[2], r3 = a[3];
    float r4 = a[4], r5 = a[5], r6 = a[6], r7 = a[7];
    r0 += a[8];  r1 += a[9];  r2 += a[10]; r3 += a[11];
    r4 += a[12]; r5 += a[13]; r6 += a[14]; r7 += a[15];
    r0 += a[16]; r1 += a[17]; r2 += a[18]; r3 += a[19];
    r4 += a[20]; r5 += a[21]; r6 += a[22]; r7 += a[23];
    r0 += a[24]; r1 += a[25]; r2 += a[26]; r3 += a[27];
    r4 += a[28]; r5 += a[29]; r6 += a[30]; r7 += a[31];
    return ((r0 + r1) + (r2 + r3)) + ((r4 + r5) + (r6 + r7));
}

/* ---------- kernel 1: np-exact per-book L2-normalize (verified) ---------- */
__global__ __launch_bounds__(256) void normC_kernel(const float* __restrict__ C,
                                                    float* __restrict__ cbT,
                                                    float* __restrict__ c2T,
                                                    unsigned int* __restrict__ ctr) {
#pragma clang fp contract(off)
    if (blockIdx.x == 0 && threadIdx.x == 0) ctr[0] = 0u;   /* reset rescan list */
    int t = blockIdx.x * 256 + threadIdx.x;
    int w = t & (NWORDS - 1);
    int b = t >> 6;
    const float* src = C + (size_t)w * DIMS + b * LWORD;
    float v[LWORD];
    #pragma unroll
    for (int q = 0; q < 8; ++q)
        *(float4*)&v[4 * q] = *(const float4*)&src[4 * q];
    float sq[LWORD];
    #pragma unroll
    for (int l = 0; l < LWORD; ++l) sq[l] = v[l] * v[l];
    float nrm = fmaxf(sqrtf(np_sum32(sq)), 1e-12f);
    float cb[LWORD];
    #pragma unroll
    for (int l = 0; l < LWORD; ++l) cb[l] = v[l] / nrm;
    float sq2[LWORD];
    #pragma unroll
    for (int l = 0; l < LWORD; ++l) sq2[l] = cb[l] * cb[l];
    float c2 = np_sum32(sq2);
    float* dst = cbT + ((size_t)b * NWORDS + w) * LWORD;
    #pragma unroll
    for (int q = 0; q < 8; ++q)
        *(float4*)&dst[4 * q] = *(const float4*)&cb[4 * q];
    c2T[b * NWORDS + w] = c2;
}

/* ---------- kernel 1b: MFMA fragment-layout codeword arrays + acc-init ---------- */
__global__ __launch_bounds__(64) void fragC_kernel(const float* __restrict__ cbT,
                                                   const float* __restrict__ c2T,
                                                   unsigned short* __restrict__ chA,
                                                   unsigned short* __restrict__ clA,
                                                   unsigned short* __restrict__ a2A,
                                                   float4* __restrict__ c2I) {
    int b = blockIdx.x;
    int l = threadIdx.x;
    int lr = l & 15, lh = l >> 4;
    #pragma unroll
    for (int wb = 0; wb < 4; ++wb) {
        size_t base = ((size_t)(b * 4 + wb) * 64 + l) * 8;
        #pragma unroll
        for (int i = 0; i < 8; ++i) {
            float f = cbT[((size_t)b * NWORDS + (wb * 16 + lr)) * LWORD + (lh * 8 + i)];
            unsigned short hh = f2bf(f);
            chA[base + i] = hh;
            clA[base + i] = f2bf(f - bf2f(hh));
        }
        float4 v;
        v.x = -0.5f * c2T[b * NWORDS + wb * 16 + lh * 4 + 0];
        v.y = -0.5f * c2T[b * NWORDS + wb * 16 + lh * 4 + 1];
        v.z = -0.5f * c2T[b * NWORDS + wb * 16 + lh * 4 + 2];
        v.w = -0.5f * c2T[b * NWORDS + wb * 16 + lh * 4 + 3];
        c2I[(size_t)(b * 4 + wb) * 64 + l] = v;
    }
    #pragma unroll
    for (int mb = 0; mb < 2; ++mb)
        #pragma unroll
        for (int kc = 0; kc < 2; ++kc) {
            size_t base = ((size_t)(b * 4 + mb * 2 + kc) * 64 + l) * 8;
            #pragma unroll
            for (int i = 0; i < 8; ++i)
                a2A[base + i] =
                    f2bf(cbT[((size_t)b * NWORDS + (kc * 32 + lh * 8 + i)) * LWORD + (mb * 16 + lr)]);
        }
}

/* ---------- kernel 2: hot path — prefetch-4, MFMA dist+softmax+Z+argmin ---------- */
__global__ __launch_bounds__(256, 4) void softpq_mfma(const float* __restrict__ x,
                                                      const unsigned short* __restrict__ chA,
                                                      const unsigned short* __restrict__ clA,
                                                      const unsigned short* __restrict__ a2A,
                                                      const float4* __restrict__ c2I,
                                                      unsigned int* __restrict__ ctr,
                                                      unsigned int* __restrict__ list,
                                                      float* __restrict__ out) {
    /* per-wave P buffer; stride 72 shorts = 144 B (16B-aligned, 2-way-free banks) */
    __shared__ __align__(16) unsigned short ps_s[4][2][16][72];   /* 18432 B */

    int u = blockIdx.x;                      /* XCD-chunked */
    int L = (u & 7) * 1024 + (u >> 3);
    int b  = L >> 6;
    int n0 = (L & 63) * 256;
    int t  = threadIdx.x;
    int lane = t & 63, wid = t >> 6;
    int h = lane >> 4, c = lane & 15;

    /* 1) issue ALL x loads (8 in flight -> HBM latency overlapped) */
    const float* xbase = x + (size_t)(n0 + wid * 64 + c) * DIMS + b * LWORD + h * 8;
    float4 xa[4], xb[4];
    #pragma unroll
    for (int g = 0; g < 4; ++g) {
        xa[g] = *(const float4*)(xbase + (size_t)g * 16 * DIMS);
        xb[g] = *(const float4*)(xbase + (size_t)g * 16 * DIMS + 4);
    }

    /* 2) frag loads (L2-hot) interleave with the x loads */
    const s16x8* chp = (const s16x8*)chA;
    const s16x8* clp = (const s16x8*)clA;
    const s16x8* a2p = (const s16x8*)a2A;
    s16x8 chf[4], clf[4], a2f[4];
    f32x4 ci[4];
    #pragma unroll
    for (int wb = 0; wb < 4; ++wb) {
        chf[wb] = chp[(size_t)(b * 4 + wb) * 64 + lane];
        clf[wb] = clp[(size_t)(b * 4 + wb) * 64 + lane];
        a2f[wb] = a2p[(size_t)(b * 4 + wb) * 64 + lane];
        float4 v = c2I[(size_t)(b * 4 + wb) * 64 + lane];
        f32x4 cv = {v.x, v.y, v.z, v.w};
        ci[wb] = cv;
    }

    /* 3) eager split of all 4 groups into bf16 hi+residual (xa/xb die here) */
    unsigned int xh[4][4], xl[4][4];
    #pragma unroll
    for (int g = 0; g < 4; ++g) {
        float xf[8] = {xa[g].x, xa[g].y, xa[g].z, xa[g].w,
                       xb[g].x, xb[g].y, xb[g].z, xb[g].w};
        #pragma unroll
        for (int j = 0; j < 4; ++j) {
            float f0 = xf[2 * j], f1 = xf[2 * j + 1];
            unsigned int ph = cvtpk_bf16(f0, f1);
            float h0 = __uint_as_float(ph << 16);
            float h1 = __uint_as_float(ph & 0xffff0000u);
            xh[g][j] = ph;
            xl[g][j] = cvtpk_bf16(f0 - h0, f1 - h1);
        }
    }

    unsigned int idxbase = (unsigned int)((n0 + wid * 64 + c) * NBOOKS + b);
    float* zbase = out + (size_t)(n0 + wid * 64 + c) * DIMS + b * LWORD + h * 4;

    #pragma unroll
    for (int g = 0; g < 4; ++g) {
        u32x4 thv = {xh[g][0], xh[g][1], xh[g][2], xh[g][3]};
        u32x4 tlv = {xl[g][0], xl[g][1], xl[g][2], xl[g][3]};
        s16x8 xhv = __builtin_bit_cast(s16x8, thv);
        s16x8 xlv = __builtin_bit_cast(s16x8, tlv);

        /* 12 S-MFMAs; acc = dot - c2/2, so d = -2*acc (x2 shift-invariant) */
        __builtin_amdgcn_s_setprio(1);
        f32x4 acc[4];
        #pragma unroll
        for (int wb = 0; wb < 4; ++wb) {
            f32x4 a = ci[wb];
            a = __builtin_amdgcn_mfma_f32_16x16x32_bf16(chf[wb], xhv, a, 0, 0, 0);
            a = __builtin_amdgcn_mfma_f32_16x16x32_bf16(chf[wb], xlv, a, 0, 0, 0);
            a = __builtin_amdgcn_mfma_f32_16x16x32_bf16(clf[wb], xhv, a, 0, 0, 0);
            acc[wb] = a;
        }
        __builtin_amdgcn_s_setprio(0);

        /* max over 16 regs (v_max3 trees) + 4 lanes */
        float q0 = fmaxf(fmaxf(acc[0][0], acc[0][1]), acc[0][2]);
        float q1 = fmaxf(fmaxf(acc[0][3], acc[1][0]), acc[1][1]);
        float q2 = fmaxf(fmaxf(acc[1][2], acc[1][3]), acc[2][0]);
        float q3 = fmaxf(fmaxf(acc[2][1], acc[2][2]), acc[2][3]);
        float q4 = fmaxf(fmaxf(acc[3][0], acc[3][1]), acc[3][2]);
        float m1 = fmaxf(fmaxf(fmaxf(q0, q1), q2), fmaxf(fmaxf(q3, q4), acc[3][3]));
        m1 = fmaxf(m1, __shfl_xor(m1, 16));
        m1 = fmaxf(m1, __shfl_xor(m1, 32));

        /* near-tie gate (2e-4 in acc-space == 4e-4 in d-space) */
        float thr = m1 - 2e-4f;
        int cnt = 0;
        #pragma unroll
        for (int wb = 0; wb < 4; ++wb)
            #pragma unroll
            for (int r = 0; r < 4; ++r) cnt += (acc[wb][r] > thr) ? 1 : 0;
        cnt += __shfl_xor(cnt, 16);
        cnt += __shfl_xor(cnt, 32);

        int wsel = 9999;
        #pragma unroll
        for (int wb = 0; wb < 4; ++wb)
            #pragma unroll
            for (int r = 0; r < 4; ++r)
                if (acc[wb][r] == m1) wsel = min(wsel, wb * 16 + h * 4 + r);
        wsel = min(wsel, __shfl_xor(wsel, 16));
        wsel = min(wsel, __shfl_xor(wsel, 32));

        /* softmax: p = exp2(T2K*(acc - m1)); arg bit-identical to round-4 form */
        float mqt = m1 * (-T2K);
        float p[16];
        float sum = 0.f;
        #pragma unroll
        for (int wb = 0; wb < 4; ++wb)
            #pragma unroll
            for (int r = 0; r < 4; ++r) {
                p[wb * 4 + r] = __builtin_amdgcn_exp2f(fmaf(T2K, acc[wb][r], mqt));
                sum += p[wb * 4 + r];
            }
        sum += __shfl_xor(sum, 16);
        sum += __shfl_xor(sum, 32);
        float inv = __builtin_amdgcn_rcpf(sum);

        /* P -> bf16 -> per-wave LDS -> B-frags (same-wave dep, no barrier) */
        unsigned int pku[8];
        #pragma unroll
        for (int k = 0; k < 8; ++k) pku[k] = cvtpk_bf16(p[2 * k], p[2 * k + 1]);
        int gb = g & 1;
        #pragma unroll
        for (int wb = 0; wb < 4; ++wb) {
            uint2 w2; w2.x = pku[2 * wb]; w2.y = pku[2 * wb + 1];
            *(uint2*)&ps_s[wid][gb][c][wb * 16 + h * 4] = w2;
        }
        s16x8 pb0 = *(const s16x8*)&ps_s[wid][gb][c][h * 8];
        s16x8 pb1 = *(const s16x8*)&ps_s[wid][gb][c][32 + h * 8];

        /* 4 Z-MFMAs + nontemporal streaming stores */
        float* zout = zbase + (size_t)g * 16 * DIMS;
        #pragma unroll
        for (int mb = 0; mb < 2; ++mb) {
            f32x4 z = {0.f, 0.f, 0.f, 0.f};
            z = __builtin_amdgcn_mfma_f32_16x16x32_bf16(a2f[mb * 2 + 0], pb0, z, 0, 0, 0);
            z = __builtin_amdgcn_mfma_f32_16x16x32_bf16(a2f[mb * 2 + 1], pb1, z, 0, 0, 0);
            f32x4 v = {z[0] * inv, z[1] * inv, z[2] * inv, z[3] * inv};
            __builtin_nontemporal_store(v, (f32x4*)(zout + mb * 16));
        }

        if (h == 0) {
            out[Z_ELEMS + idxbase + (unsigned int)g * 16u * NBOOKS] = (float)wsel;
            if (cnt >= 2) {                       /* defer np-exact rescan */
                unsigned int pos = atomicAdd(ctr, 1u);
                unsigned int row = (unsigned int)(n0 + wid * 64 + g * 16 + c);
                if (pos < LIST_CAP) list[pos] = (row << 7) | (unsigned int)b;
            }
        }
    }
}

/* ---------- kernel 3: np-exact rescan of flagged near-tie rows ---------- */
__global__ __launch_bounds__(256) void rescan_kernel(const float* __restrict__ x,
                                                     const float* __restrict__ cbT,
                                                     const float* __restrict__ c2T,
                                                     const unsigned int* __restrict__ ctr,
                                                     const unsigned int* __restrict__ list,
                                                     float* __restrict__ out) {
    unsigned int n = *ctr;
    if (n > LIST_CAP) n = LIST_CAP;
    for (unsigned int i = blockIdx.x * 256 + threadIdx.x; i < n; i += 64u * 256u) {
        unsigned int e = list[i];
        int row = (int)(e >> 7);
        int b   = (int)(e & 127u);
        const float* xrow = x + (size_t)row * DIMS + b * LWORD;
        float xr2[LWORD], sq[LWORD];
        #pragma unroll
        for (int q2 = 0; q2 < 8; ++q2)
            *(float4*)&xr2[q2 * 4] = *(const float4*)(xrow + q2 * 4);
        #pragma unroll
        for (int l = 0; l < LWORD; ++l) sq[l] = xr2[l] * xr2[l];
        float x2n = np_sum32(sq);
        float best = __builtin_inff();
        int wbest = 0;
        const float* Cb = cbT + (size_t)b * NWORDS * LWORD;
        for (int w2 = 0; w2 < NWORDS; ++w2) {
            const float* cw = Cb + (size_t)w2 * LWORD;
            double accd = 0.0;
            #pragma unroll
            for (int l = 0; l < LWORD; ++l)
                accd = fma((double)xr2[l], (double)cw[l], accd);
            float xcf = (float)accd;
            float dnp;
            {
#pragma clang fp contract(off)
                float s1 = x2n + c2T[b * NWORDS + w2];
                float s2 = 2.0f * xcf;
                dnp = s1 - s2;
            }
            if (dnp < best) { best = dnp; wbest = w2; }
        }
        out[Z_ELEMS + (size_t)row * NBOOKS + b] = (float)wbest;
    }
}

extern "C" void kernel_launch(void* const* d_in, const int* in_sizes, int n_in,
                              void* d_out, int out_size, void* d_ws, size_t ws_size,
                              hipStream_t stream) {
    const float* x = (const float*)d_in[0];
    const float* C = (const float*)d_in[1];
    float* out = (float*)d_out;
    char* ws = (char*)d_ws;
    float* cbT = (float*)(ws + CBT_OFF);
    float* c2T = (float*)(ws + C2T_OFF);
    unsigned short* chA = (unsigned short*)(ws + CHA_OFF);
    unsigned short* clA = (unsigned short*)(ws + CLA_OFF);
    unsigned short* a2A = (unsigned short*)(ws + A2_OFF);
    float4* c2I = (float4*)(ws + C2I_OFF);
    unsigned int* ctr  = (unsigned int*)(ws + CTR_OFF);
    unsigned int* list = (unsigned int*)(ws + LIST_OFF);

    normC_kernel<<<32, 256, 0, stream>>>(C, cbT, c2T, ctr);
    fragC_kernel<<<128, 64, 0, stream>>>(cbT, c2T, chA, clA, a2A, c2I);
    softpq_mfma<<<8192, 256, 0, stream>>>(x, chA, clA, a2A, c2I, ctr, list, out);
    rescan_kernel<<<64, 256, 0, stream>>>(x, cbT, c2T, ctr, list, out);
}

// Round 6
// 227.544 us; speedup vs baseline: 1.3763x; 1.3763x over previous
//
#include <hip/hip_runtime.h>
#include <math.h>

#define NROWS   16384
#define NBOOKS  128
#define NWORDS  64
#define LWORD   32
#define DIMS    4096
#define TAU_K   14.4269504088896340736f   /* 10 * log2(e)  */
#define T2K     28.8539008177792681472f   /* 20 * log2(e)  */
#define Z_ELEMS 67108864ull               /* 16384*4096    */

typedef __attribute__((ext_vector_type(8))) short s16x8;
typedef __attribute__((ext_vector_type(4))) float f32x4;
typedef __attribute__((ext_vector_type(4))) unsigned int u32x4;

/* ws layout (bytes) */
#define CBT_OFF  0u           /* f32 [128][64][32] np-normalized codewords  */
#define C2T_OFF  1048576u     /* f32 [128][64]                              */
#define CHA_OFF  1081344u     /* bf16 S-frags hi                            */
#define CLA_OFF  1605632u     /* bf16 S-frags lo                            */
#define A2_OFF   2129920u     /* bf16 Z-frags                               */
#define C2I_OFF  2654208u     /* f32x4 acc-init = -c2/2                     */
#define CTR_OFF  3178496u     /* u32 rescan counter                         */
#define LIST_OFF 3178624u     /* u32[131072] packed (row<<7)|b              */
#define LIST_CAP 131072u
#define IDXW_OFF 4194304u     /* f32 [128][16384] coalesced idx staging     */
#define WS_NEED  (IDXW_OFF + (size_t)NBOOKS * NROWS * 4u)

__device__ __forceinline__ unsigned short f2bf(float f) {
    unsigned int u = __float_as_uint(f);
    unsigned int r = (u + 0x7FFFu + ((u >> 16) & 1u)) >> 16;   /* RNE */
    return (unsigned short)r;
}
__device__ __forceinline__ float bf2f(unsigned short s) {
    return __uint_as_float(((unsigned int)s) << 16);
}
__device__ __forceinline__ unsigned int cvtpk_bf16(float lo, float hi) {
    unsigned int r;
    asm("v_cvt_pk_bf16_f32 %0, %1, %2" : "=v"(r) : "v"(lo), "v"(hi));  /* RNE */
    return r;
}

/* numpy pairwise-sum replica for n=32 f32 (exact order, no contraction) */
__device__ __forceinline__ float np_sum32(const float* a) {
#pragma clang fp contract(off)
    float r0 = a[0], r1 = a[1], r2 = a[2], r3 = a[3];
    float r4 = a[4], r5 = a[5], r6 = a[6], r7 = a[7];
    r0 += a[8];  r1 += a[9];  r2 += a[10]; r3 += a[11];
    r4 += a[12]; r5 += a[13]; r6 += a[14]; r7 += a[15];
    r0 += a[16]; r1 += a[17]; r2 += a[18]; r3 += a[19];
    r4 += a[20]; r5 += a[21]; r6 += a[22]; r7 += a[23];
    r0 += a[24]; r1 += a[25]; r2 += a[26]; r3 += a[27];
    r4 += a[28]; r5 += a[29]; r6 += a[30]; r7 += a[31];
    return ((r0 + r1) + (r2 + r3)) + ((r4 + r5) + (r6 + r7));
}

/* ---------- kernel 1: np-exact per-book L2-normalize (verified) ---------- */
__global__ __launch_bounds__(256) void normC_kernel(const float* __restrict__ C,
                                                    float* __restrict__ cbT,
                                                    float* __restrict__ c2T,
                                                    unsigned int* __restrict__ ctr) {
#pragma clang fp contract(off)
    if (blockIdx.x == 0 && threadIdx.x == 0) ctr[0] = 0u;
    int t = blockIdx.x * 256 + threadIdx.x;
    int w = t & (NWORDS - 1);
    int b = t >> 6;
    const float* src = C + (size_t)w * DIMS + b * LWORD;
    float v[LWORD];
    #pragma unroll
    for (int q = 0; q < 8; ++q)
        *(float4*)&v[4 * q] = *(const float4*)&src[4 * q];
    float sq[LWORD];
    #pragma unroll
    for (int l = 0; l < LWORD; ++l) sq[l] = v[l] * v[l];
    float nrm = fmaxf(sqrtf(np_sum32(sq)), 1e-12f);
    float cb[LWORD];
    #pragma unroll
    for (int l = 0; l < LWORD; ++l) cb[l] = v[l] / nrm;
    float sq2[LWORD];
    #pragma unroll
    for (int l = 0; l < LWORD; ++l) sq2[l] = cb[l] * cb[l];
    float c2 = np_sum32(sq2);
    float* dst = cbT + ((size_t)b * NWORDS + w) * LWORD;
    #pragma unroll
    for (int q = 0; q < 8; ++q)
        *(float4*)&dst[4 * q] = *(const float4*)&cb[4 * q];
    c2T[b * NWORDS + w] = c2;
}

/* ---------- kernel 1b: MFMA fragment-layout codeword arrays + acc-init ---------- */
__global__ __launch_bounds__(64) void fragC_kernel(const float* __restrict__ cbT,
                                                   const float* __restrict__ c2T,
                                                   unsigned short* __restrict__ chA,
                                                   unsigned short* __restrict__ clA,
                                                   unsigned short* __restrict__ a2A,
                                                   float4* __restrict__ c2I) {
    int b = blockIdx.x;
    int l = threadIdx.x;
    int lr = l & 15, lh = l >> 4;
    #pragma unroll
    for (int wb = 0; wb < 4; ++wb) {
        size_t base = ((size_t)(b * 4 + wb) * 64 + l) * 8;
        #pragma unroll
        for (int i = 0; i < 8; ++i) {
            float f = cbT[((size_t)b * NWORDS + (wb * 16 + lr)) * LWORD + (lh * 8 + i)];
            unsigned short hh = f2bf(f);
            chA[base + i] = hh;
            clA[base + i] = f2bf(f - bf2f(hh));
        }
        float4 v;
        v.x = -0.5f * c2T[b * NWORDS + wb * 16 + lh * 4 + 0];
        v.y = -0.5f * c2T[b * NWORDS + wb * 16 + lh * 4 + 1];
        v.z = -0.5f * c2T[b * NWORDS + wb * 16 + lh * 4 + 2];
        v.w = -0.5f * c2T[b * NWORDS + wb * 16 + lh * 4 + 3];
        c2I[(size_t)(b * 4 + wb) * 64 + l] = v;
    }
    #pragma unroll
    for (int mb = 0; mb < 2; ++mb)
        #pragma unroll
        for (int kc = 0; kc < 2; ++kc) {
            size_t base = ((size_t)(b * 4 + mb * 2 + kc) * 64 + l) * 8;
            #pragma unroll
            for (int i = 0; i < 8; ++i)
                a2A[base + i] =
                    f2bf(cbT[((size_t)b * NWORDS + (kc * 32 + lh * 8 + i)) * LWORD + (mb * 16 + lr)]);
        }
}

/* ---------- per-group tail: softmax + P-pack + Z + idx (shared body) ---------- */
/* numerics identical to the verified r5 path */
#define GROUP_TAIL(ACC, G)                                                             \
  {                                                                                    \
    float q0 = fmaxf(fmaxf(ACC[0][0], ACC[0][1]), ACC[0][2]);                          \
    float q1 = fmaxf(fmaxf(ACC[0][3], ACC[1][0]), ACC[1][1]);                          \
    float q2 = fmaxf(fmaxf(ACC[1][2], ACC[1][3]), ACC[2][0]);                          \
    float q3 = fmaxf(fmaxf(ACC[2][1], ACC[2][2]), ACC[2][3]);                          \
    float q4 = fmaxf(fmaxf(ACC[3][0], ACC[3][1]), ACC[3][2]);                          \
    float m1 = fmaxf(fmaxf(fmaxf(q0, q1), q2), fmaxf(fmaxf(q3, q4), ACC[3][3]));       \
    m1 = fmaxf(m1, __shfl_xor(m1, 16));                                                \
    m1 = fmaxf(m1, __shfl_xor(m1, 32));                                                \
    float thr = m1 - 2e-4f;                                                            \
    int cnt = 0;                                                                       \
    _Pragma("unroll")                                                                  \
    for (int wb = 0; wb < 4; ++wb)                                                     \
      _Pragma("unroll")                                                                \
      for (int r = 0; r < 4; ++r) cnt += (ACC[wb][r] > thr) ? 1 : 0;                   \
    cnt += __shfl_xor(cnt, 16);                                                        \
    cnt += __shfl_xor(cnt, 32);                                                        \
    int wsel = 9999;                                                                   \
    _Pragma("unroll")                                                                  \
    for (int wb = 0; wb < 4; ++wb)                                                     \
      _Pragma("unroll")                                                                \
      for (int r = 0; r < 4; ++r)                                                      \
        if (ACC[wb][r] == m1) wsel = min(wsel, wb * 16 + h * 4 + r);                   \
    wsel = min(wsel, __shfl_xor(wsel, 16));                                            \
    wsel = min(wsel, __shfl_xor(wsel, 32));                                            \
    float mqt = m1 * (-T2K);                                                           \
    float p[16];                                                                       \
    float sum = 0.f;                                                                   \
    _Pragma("unroll")                                                                  \
    for (int wb = 0; wb < 4; ++wb)                                                     \
      _Pragma("unroll")                                                                \
      for (int r = 0; r < 4; ++r) {                                                    \
        p[wb * 4 + r] = __builtin_amdgcn_exp2f(fmaf(T2K, ACC[wb][r], mqt));            \
        sum += p[wb * 4 + r];                                                          \
      }                                                                                \
    sum += __shfl_xor(sum, 16);                                                        \
    sum += __shfl_xor(sum, 32);                                                        \
    float inv = __builtin_amdgcn_rcpf(sum);                                            \
    unsigned int pku[8];                                                               \
    _Pragma("unroll")                                                                  \
    for (int k = 0; k < 8; ++k) pku[k] = cvtpk_bf16(p[2 * k], p[2 * k + 1]);           \
    _Pragma("unroll")                                                                  \
    for (int wb = 0; wb < 4; ++wb) {                                                   \
      uint2 w2; w2.x = pku[2 * wb]; w2.y = pku[2 * wb + 1];                            \
      *(uint2*)&ps_s[wid][(G) & 1][c][wb * 16 + h * 4] = w2;                           \
    }                                                                                  \
    s16x8 pb0 = *(const s16x8*)&ps_s[wid][(G) & 1][c][h * 8];                          \
    s16x8 pb1 = *(const s16x8*)&ps_s[wid][(G) & 1][c][32 + h * 8];                     \
    float* zout = zbase + (size_t)(G) * 16 * DIMS;                                     \
    _Pragma("unroll")                                                                  \
    for (int mb = 0; mb < 2; ++mb) {                                                   \
      f32x4 z = {0.f, 0.f, 0.f, 0.f};                                                  \
      z = __builtin_amdgcn_mfma_f32_16x16x32_bf16(a2f[mb * 2 + 0], pb0, z, 0, 0, 0);   \
      z = __builtin_amdgcn_mfma_f32_16x16x32_bf16(a2f[mb * 2 + 1], pb1, z, 0, 0, 0);   \
      float4 v;                                                                        \
      v.x = z[0] * inv; v.y = z[1] * inv; v.z = z[2] * inv; v.w = z[3] * inv;          \
      *(float4*)(zout + mb * 16) = v;                                                  \
    }                                                                                  \
    if (h == 0) {                                                                      \
      int row = n0 + wid * 64 + (G) * 16 + c;                                          \
      idxd[(size_t)row * rs + (size_t)b * bs] = (float)wsel;                           \
      if (cnt >= 2) {                                                                  \
        unsigned int pos = atomicAdd(ctr, 1u);                                         \
        if (pos < LIST_CAP) list[pos] = ((unsigned int)row << 7) | (unsigned int)b;    \
      }                                                                                \
    }                                                                                  \
  }

/* ---------- kernel 2: hot path — prefetch-4, paired-group pipeline ---------- */
__global__ __launch_bounds__(256, 3) void softpq_mfma(const float* __restrict__ x,
                                                      const unsigned short* __restrict__ chA,
                                                      const unsigned short* __restrict__ clA,
                                                      const unsigned short* __restrict__ a2A,
                                                      const float4* __restrict__ c2I,
                                                      unsigned int* __restrict__ ctr,
                                                      unsigned int* __restrict__ list,
                                                      float* __restrict__ idxd,
                                                      size_t rs, size_t bs,
                                                      float* __restrict__ out) {
    __shared__ __align__(16) unsigned short ps_s[4][2][16][72];   /* 18432 B */

    int u = blockIdx.x;                      /* XCD-chunked */
    int L = (u & 7) * 1024 + (u >> 3);
    int b  = L >> 6;
    int n0 = (L & 63) * 256;
    int t  = threadIdx.x;
    int lane = t & 63, wid = t >> 6;
    int h = lane >> 4, c = lane & 15;

    /* 1) issue ALL x loads (8 in flight) */
    const float* xbase = x + (size_t)(n0 + wid * 64 + c) * DIMS + b * LWORD + h * 8;
    float4 xa[4], xb[4];
    #pragma unroll
    for (int g = 0; g < 4; ++g) {
        xa[g] = *(const float4*)(xbase + (size_t)g * 16 * DIMS);
        xb[g] = *(const float4*)(xbase + (size_t)g * 16 * DIMS + 4);
    }

    /* 2) frag loads (L2-hot) interleave with x loads */
    const s16x8* chp = (const s16x8*)chA;
    const s16x8* clp = (const s16x8*)clA;
    const s16x8* a2p = (const s16x8*)a2A;
    s16x8 chf[4], clf[4], a2f[4];
    f32x4 ci[4];
    #pragma unroll
    for (int wb = 0; wb < 4; ++wb) {
        chf[wb] = chp[(size_t)(b * 4 + wb) * 64 + lane];
        clf[wb] = clp[(size_t)(b * 4 + wb) * 64 + lane];
        a2f[wb] = a2p[(size_t)(b * 4 + wb) * 64 + lane];
        float4 v = c2I[(size_t)(b * 4 + wb) * 64 + lane];
        f32x4 cv = {v.x, v.y, v.z, v.w};
        ci[wb] = cv;
    }

    /* 3) eager split into bf16 hi + residual */
    unsigned int xh[4][4], xl[4][4];
    #pragma unroll
    for (int g = 0; g < 4; ++g) {
        float xf[8] = {xa[g].x, xa[g].y, xa[g].z, xa[g].w,
                       xb[g].x, xb[g].y, xb[g].z, xb[g].w};
        #pragma unroll
        for (int j = 0; j < 4; ++j) {
            float f0 = xf[2 * j], f1 = xf[2 * j + 1];
            unsigned int ph = cvtpk_bf16(f0, f1);
            float h0 = __uint_as_float(ph << 16);
            float h1 = __uint_as_float(ph & 0xffff0000u);
            xh[g][j] = ph;
            xl[g][j] = cvtpk_bf16(f0 - h0, f1 - h1);
        }
    }

    float* zbase = out + (size_t)(n0 + wid * 64 + c) * DIMS + b * LWORD + h * 4;

    /* paired-group pipeline: 24 MFMAs back-to-back, then the two VALU tails
       (Z-MFMA of g0 overlaps softmax VALU of g1) */
    #pragma unroll
    for (int gp = 0; gp < 2; ++gp) {
        int g0 = gp * 2, g1 = gp * 2 + 1;
        u32x4 th0 = {xh[g0][0], xh[g0][1], xh[g0][2], xh[g0][3]};
        u32x4 tl0 = {xl[g0][0], xl[g0][1], xl[g0][2], xl[g0][3]};
        u32x4 th1 = {xh[g1][0], xh[g1][1], xh[g1][2], xh[g1][3]};
        u32x4 tl1 = {xl[g1][0], xl[g1][1], xl[g1][2], xl[g1][3]};
        s16x8 xh0 = __builtin_bit_cast(s16x8, th0);
        s16x8 xl0 = __builtin_bit_cast(s16x8, tl0);
        s16x8 xh1 = __builtin_bit_cast(s16x8, th1);
        s16x8 xl1 = __builtin_bit_cast(s16x8, tl1);

        __builtin_amdgcn_s_setprio(1);
        f32x4 acc0[4], acc1[4];
        #pragma unroll
        for (int wb = 0; wb < 4; ++wb) {
            f32x4 a = ci[wb];
            a = __builtin_amdgcn_mfma_f32_16x16x32_bf16(chf[wb], xh0, a, 0, 0, 0);
            a = __builtin_amdgcn_mfma_f32_16x16x32_bf16(chf[wb], xl0, a, 0, 0, 0);
            a = __builtin_amdgcn_mfma_f32_16x16x32_bf16(clf[wb], xh0, a, 0, 0, 0);
            acc0[wb] = a;
        }
        #pragma unroll
        for (int wb = 0; wb < 4; ++wb) {
            f32x4 a = ci[wb];
            a = __builtin_amdgcn_mfma_f32_16x16x32_bf16(chf[wb], xh1, a, 0, 0, 0);
            a = __builtin_amdgcn_mfma_f32_16x16x32_bf16(chf[wb], xl1, a, 0, 0, 0);
            a = __builtin_amdgcn_mfma_f32_16x16x32_bf16(clf[wb], xh1, a, 0, 0, 0);
            acc1[wb] = a;
        }
        __builtin_amdgcn_s_setprio(0);

        GROUP_TAIL(acc0, g0)
        GROUP_TAIL(acc1, g1)
    }
}

/* ---------- kernel 3: np-exact rescan of flagged near-tie rows ---------- */
__global__ __launch_bounds__(256) void rescan_kernel(const float* __restrict__ x,
                                                     const float* __restrict__ cbT,
                                                     const float* __restrict__ c2T,
                                                     const unsigned int* __restrict__ ctr,
                                                     const unsigned int* __restrict__ list,
                                                     float* __restrict__ idxd,
                                                     size_t rs, size_t bs) {
    unsigned int n = *ctr;
    if (n > LIST_CAP) n = LIST_CAP;
    for (unsigned int i = blockIdx.x * 256 + threadIdx.x; i < n; i += 64u * 256u) {
        unsigned int e = list[i];
        int row = (int)(e >> 7);
        int b   = (int)(e & 127u);
        const float* xrow = x + (size_t)row * DIMS + b * LWORD;
        float xr2[LWORD], sq[LWORD];
        #pragma unroll
        for (int q2 = 0; q2 < 8; ++q2)
            *(float4*)&xr2[q2 * 4] = *(const float4*)(xrow + q2 * 4);
        #pragma unroll
        for (int l = 0; l < LWORD; ++l) sq[l] = xr2[l] * xr2[l];
        float x2n = np_sum32(sq);
        float best = __builtin_inff();
        int wbest = 0;
        const float* Cb = cbT + (size_t)b * NWORDS * LWORD;
        for (int w2 = 0; w2 < NWORDS; ++w2) {
            const float* cw = Cb + (size_t)w2 * LWORD;
            double accd = 0.0;
            #pragma unroll
            for (int l = 0; l < LWORD; ++l)
                accd = fma((double)xr2[l], (double)cw[l], accd);
            float xcf = (float)accd;
            float dnp;
            {
#pragma clang fp contract(off)
                float s1 = x2n + c2T[b * NWORDS + w2];
                float s2 = 2.0f * xcf;
                dnp = s1 - s2;
            }
            if (dnp < best) { best = dnp; wbest = w2; }
        }
        idxd[(size_t)row * rs + (size_t)b * bs] = (float)wbest;
    }
}

/* ---------- kernel 4: [book][row] -> [row][book] idx transpose ---------- */
__global__ __launch_bounds__(256) void idxT_kernel(const float* __restrict__ idxw,
                                                   float* __restrict__ out) {
    __shared__ float tile[NBOOKS][65];        /* 64 rows per block, +1 pad */
    int r0 = blockIdx.x * 64;
    int t  = threadIdx.x;
    #pragma unroll
    for (int it = 0; it < 32; ++it) {
        int id = it * 256 + t;
        int b  = id >> 6;
        int r  = id & 63;
        tile[b][r] = idxw[(size_t)b * NROWS + r0 + r];
    }
    __syncthreads();
    #pragma unroll
    for (int it = 0; it < 32; ++it) {
        int id  = it * 256 + t;
        int row = id >> 7;
        int bb  = id & 127;
        out[Z_ELEMS + (size_t)(r0 + row) * NBOOKS + bb] = tile[bb][row];
    }
}

extern "C" void kernel_launch(void* const* d_in, const int* in_sizes, int n_in,
                              void* d_out, int out_size, void* d_ws, size_t ws_size,
                              hipStream_t stream) {
    const float* x = (const float*)d_in[0];
    const float* C = (const float*)d_in[1];
    float* out = (float*)d_out;
    char* ws = (char*)d_ws;
    float* cbT = (float*)(ws + CBT_OFF);
    float* c2T = (float*)(ws + C2T_OFF);
    unsigned short* chA = (unsigned short*)(ws + CHA_OFF);
    unsigned short* clA = (unsigned short*)(ws + CLA_OFF);
    unsigned short* a2A = (unsigned short*)(ws + A2_OFF);
    float4* c2I = (float4*)(ws + C2I_OFF);
    unsigned int* ctr  = (unsigned int*)(ws + CTR_OFF);
    unsigned int* list = (unsigned int*)(ws + LIST_OFF);

    bool big = (ws_size >= WS_NEED);
    float* idxw = big ? (float*)(ws + IDXW_OFF) : (out + Z_ELEMS);
    size_t rs = big ? 1 : (size_t)NBOOKS;            /* row stride  */
    size_t bs = big ? (size_t)NROWS : 1;             /* book stride */

    normC_kernel<<<32, 256, 0, stream>>>(C, cbT, c2T, ctr);
    fragC_kernel<<<128, 64, 0, stream>>>(cbT, c2T, chA, clA, a2A, c2I);
    softpq_mfma<<<8192, 256, 0, stream>>>(x, chA, clA, a2A, c2I, ctr, list,
                                          idxw, rs, bs, out);
    rescan_kernel<<<64, 256, 0, stream>>>(x, cbT, c2T, ctr, list, idxw, rs, bs);
    if (big) idxT_kernel<<<256, 256, 0, stream>>>(idxw, out);
}